// Round 2
// baseline (145.033 us; speedup 1.0000x reference)
//
#include <hip/hip_runtime.h>
#include <math.h>

// original: [4,3,512,512] f32 ; degraded: [4,7,3,512,512] f32
// logits: [8,32,32] f32 ; topk: int (=2) ; out: [4,3,512,512] f32
//
// out[b,c,h,w] = sum_n stacked[b,n,c,h,w] * wfin[n,h,w]
// wfin = renormalized top-k mask of softmax(bilinear_upsample_16x(logits)).
//
// Each thread handles 2 consecutive pixels (float2 loads/stores, 8B/lane).
// 2-aligned pixel pairs never straddle a low-res interpolation cell
// (cell boundaries at w = 8 + 16k, always even+...8 -> never between 2k,2k+1).

#define HW_ (512 * 512)

__global__ __launch_bounds__(256) void rain_combine_v2(
    const float* __restrict__ orig,
    const float* __restrict__ deg,
    const float* __restrict__ logits,
    const int* __restrict__ topk_p,
    float* __restrict__ out)
{
    const int g = blockIdx.x * 256 + threadIdx.x;   // pixel-pair id [0, 131072)
    const int p0 = g << 1;
    const int h = p0 >> 9;
    const int w0 = p0 & 511;

    // ---- bilinear taps (half-pixel centers, 16x upscale, edge clamp) ----
    const float yc = (h + 0.5f) * 0.0625f - 0.5f;
    const float yf = floorf(yc);
    const float fy = yc - yf;
    const int y0 = (int)yf;
    const int y0c = max(y0, 0), y1c = min(y0 + 1, 31);

    const float xc0 = (w0 + 0.5f) * 0.0625f - 0.5f;
    const float xf = floorf(xc0);
    const int x0 = (int)xf;
    const int x0c = max(x0, 0), x1c = min(x0 + 1, 31);
    const float fx0 = xc0 - xf;
    const float xc1 = (w0 + 1.5f) * 0.0625f - 0.5f;
    const float fx1 = xc1 - xf;            // same cell, same floor

    const int o00 = y0c * 32 + x0c;
    const int o01 = y0c * 32 + x1c;
    const int o10 = y1c * 32 + x0c;
    const int o11 = y1c * 32 + x1c;

    // per-pixel bilinear weights (identical formula to reference path)
    const float A00 = (1.f - fy) * (1.f - fx0), A01 = (1.f - fy) * fx0;
    const float A10 = fy * (1.f - fx0),         A11 = fy * fx0;
    const float B00 = (1.f - fy) * (1.f - fx1), B01 = (1.f - fy) * fx1;
    const float B10 = fy * (1.f - fx1),         B11 = fy * fx1;

    float u[2][8];
    #pragma unroll
    for (int n = 0; n < 8; ++n) {
        const float* Lb = logits + n * 1024;
        const float t00 = Lb[o00], t01 = Lb[o01], t10 = Lb[o10], t11 = Lb[o11];
        u[0][n] = A00 * t00 + A01 * t01 + A10 * t10 + A11 * t11;
        u[1][n] = B00 * t00 + B01 * t01 + B10 * t10 + B11 * t11;
    }

    const int k = *topk_p;   // = 2

    // ---- per-pixel: softmax -> rank-based k-th largest -> renormalized wf ----
    float wf[2][8];
    #pragma unroll
    for (int i = 0; i < 2; ++i) {
        float mx = u[i][0];
        #pragma unroll
        for (int n = 1; n < 8; ++n) mx = fmaxf(mx, u[i][n]);
        float e[8];
        float s = 0.f;
        #pragma unroll
        for (int n = 0; n < 8; ++n) { e[n] = expf(u[i][n] - mx); s += e[n]; }
        float wg[8];
        #pragma unroll
        for (int n = 0; n < 8; ++n) wg[n] = e[n] / s;

        // k-th largest with jax.lax.top_k-compatible tie handling
        float kth = -INFINITY;
        #pragma unroll
        for (int n = 0; n < 8; ++n) {
            int gt = 0, ge = 0;
            #pragma unroll
            for (int j = 0; j < 8; ++j) {
                gt += (wg[j] >  wg[n]);
                ge += (wg[j] >= wg[n]);
            }
            if (gt < k && ge >= k) kth = wg[n];
        }

        float S = 0.f;
        #pragma unroll
        for (int n = 0; n < 8; ++n) if (wg[n] >= kth) S += wg[n];
        #pragma unroll
        for (int n = 0; n < 8; ++n) wf[i][n] = (wg[n] >= kth) ? (wg[n] / S) : 0.f;
    }

    // ---- combine: only touch branches some pixel of this thread kept ----
    float acc[24];     // [(b*3+c)][pix]
    #pragma unroll
    for (int i = 0; i < 24; ++i) acc[i] = 0.f;

    #pragma unroll
    for (int n = 0; n < 8; ++n) {
        const bool need = (wf[0][n] != 0.f) || (wf[1][n] != 0.f);
        if (need) {                      // exec-masked; block skipped when no lane needs n
            const float w0n = wf[0][n], w1n = wf[1][n];
            const float* base = (n == 0) ? (orig + p0)
                                         : (deg + (size_t)(n - 1) * 3 * HW_ + p0);
            const int bstr = (n == 0) ? 3 * HW_ : 21 * HW_;
            #pragma unroll
            for (int b = 0; b < 4; ++b) {
                #pragma unroll
                for (int c = 0; c < 3; ++c) {
                    const float2 v = *reinterpret_cast<const float2*>(
                        base + (size_t)b * bstr + (size_t)c * HW_);
                    acc[(b * 3 + c) * 2 + 0] += w0n * v.x;
                    acc[(b * 3 + c) * 2 + 1] += w1n * v.y;
                }
            }
        }
    }

    #pragma unroll
    for (int b = 0; b < 4; ++b) {
        #pragma unroll
        for (int c = 0; c < 3; ++c) {
            float2 o;
            o.x = acc[(b * 3 + c) * 2 + 0];
            o.y = acc[(b * 3 + c) * 2 + 1];
            *reinterpret_cast<float2*>(out + (size_t)(b * 3 + c) * HW_ + p0) = o;
        }
    }
}

extern "C" void kernel_launch(void* const* d_in, const int* in_sizes, int n_in,
                              void* d_out, int out_size, void* d_ws, size_t ws_size,
                              hipStream_t stream) {
    const float* orig   = (const float*)d_in[0];
    const float* deg    = (const float*)d_in[1];
    const float* logits = (const float*)d_in[2];
    const int*   topk   = (const int*)d_in[3];
    float* out = (float*)d_out;

    const int groups = (512 * 512) / 2;            // 131072 pixel pairs
    rain_combine_v2<<<dim3(groups / 256), dim3(256), 0, stream>>>(
        orig, deg, logits, topk, out);
}

// Round 4
// 143.475 us; speedup vs baseline: 1.0109x; 1.0109x over previous
//
#include <hip/hip_runtime.h>
#include <math.h>

// original: [4,3,512,512] f32 ; degraded: [4,7,3,512,512] f32
// logits: [8,32,32] f32 ; topk: int (=2) ; out: [4,3,512,512] f32
//
// v3 (resubmit — round-3 bench lost to GPU acquisition timeout):
// grid.y = batch (4 planes). Each thread: 2 consecutive pixels, 3 channels
// of ONE batch. 524k threads -> 32 waves/CU (vs 8 in v2) for latency hiding.
// Renormalized top-k softmax computed as e[n]/sum_kept(e) (global softmax
// denominator cancels algebraically).

#define HW_ (512 * 512)

__global__ __launch_bounds__(256) void rain_combine_v3(
    const float* __restrict__ orig,    // [4,3,HW]
    const float* __restrict__ deg,     // [4,7,3,HW]
    const float* __restrict__ logits,  // [8,32,32]
    const int* __restrict__ topk_p,
    float* __restrict__ out)           // [4,3,HW]
{
    const int g  = blockIdx.x * 256 + threadIdx.x;  // pixel-pair id [0, 131072)
    const int b  = blockIdx.y;                      // batch plane
    const int p0 = g << 1;
    const int h  = p0 >> 9;
    const int w0 = p0 & 511;

    // ---- bilinear taps (half-pixel centers, 16x upscale, edge clamp) ----
    const float yc = (h + 0.5f) * 0.0625f - 0.5f;
    const float yf = floorf(yc);
    const float fy = yc - yf;
    const int y0 = (int)yf;
    const int y0c = max(y0, 0), y1c = min(y0 + 1, 31);

    const float xc0 = (w0 + 0.5f) * 0.0625f - 0.5f;
    const float xf = floorf(xc0);
    const int x0 = (int)xf;
    const int x0c = max(x0, 0), x1c = min(x0 + 1, 31);
    const float fx0 = xc0 - xf;
    const float fx1 = fx0 + 0.0625f;     // second pixel, same cell

    const int o00 = y0c * 32 + x0c;
    const int o01 = y0c * 32 + x1c;
    const int o10 = y1c * 32 + x0c;
    const int o11 = y1c * 32 + x1c;

    const float A00 = (1.f - fy) * (1.f - fx0), A01 = (1.f - fy) * fx0;
    const float A10 = fy * (1.f - fx0),         A11 = fy * fx0;
    const float B00 = (1.f - fy) * (1.f - fx1), B01 = (1.f - fy) * fx1;
    const float B10 = fy * (1.f - fx1),         B11 = fy * fx1;

    float u[2][8];
    #pragma unroll
    for (int n = 0; n < 8; ++n) {
        const float* Lb = logits + n * 1024;
        const float t00 = Lb[o00], t01 = Lb[o01], t10 = Lb[o10], t11 = Lb[o11];
        u[0][n] = A00 * t00 + A01 * t01 + A10 * t10 + A11 * t11;
        u[1][n] = B00 * t00 + B01 * t01 + B10 * t10 + B11 * t11;
    }

    const int k = *topk_p;   // = 2

    // ---- per-pixel: exp -> rank-based k-th largest -> wf = e / sum_kept(e) ----
    float wf[2][8];
    #pragma unroll
    for (int i = 0; i < 2; ++i) {
        float mx = u[i][0];
        #pragma unroll
        for (int n = 1; n < 8; ++n) mx = fmaxf(mx, u[i][n]);
        float e[8];
        #pragma unroll
        for (int n = 0; n < 8; ++n) e[n] = expf(u[i][n] - mx);

        // k-th largest of e[] (ranks identical to softmax weights; exp monotone)
        float kth = -INFINITY;
        #pragma unroll
        for (int n = 0; n < 8; ++n) {
            int gt = 0, ge = 0;
            #pragma unroll
            for (int j = 0; j < 8; ++j) {
                gt += (e[j] >  e[n]);
                ge += (e[j] >= e[n]);
            }
            if (gt < k && ge >= k) kth = e[n];
        }

        float S = 0.f;
        #pragma unroll
        for (int n = 0; n < 8; ++n) if (e[n] >= kth) S += e[n];
        const float rS = 1.f / S;
        #pragma unroll
        for (int n = 0; n < 8; ++n) wf[i][n] = (e[n] >= kth) ? (e[n] * rS) : 0.f;
    }

    // ---- combine this batch's 3 channels; only load kept branches ----
    float acc[6];
    #pragma unroll
    for (int i = 0; i < 6; ++i) acc[i] = 0.f;

    #pragma unroll
    for (int n = 0; n < 8; ++n) {
        const bool need = (wf[0][n] != 0.f) || (wf[1][n] != 0.f);
        if (need) {
            const float w0n = wf[0][n], w1n = wf[1][n];
            const float* base = (n == 0)
                ? (orig + (size_t)b * 3 * HW_ + p0)
                : (deg + ((size_t)b * 21 + (size_t)(n - 1) * 3) * HW_ + p0);
            #pragma unroll
            for (int c = 0; c < 3; ++c) {
                const float2 v = *reinterpret_cast<const float2*>(base + (size_t)c * HW_);
                acc[c * 2 + 0] += w0n * v.x;
                acc[c * 2 + 1] += w1n * v.y;
            }
        }
    }

    float* ob = out + (size_t)b * 3 * HW_ + p0;
    #pragma unroll
    for (int c = 0; c < 3; ++c) {
        float2 o;
        o.x = acc[c * 2 + 0];
        o.y = acc[c * 2 + 1];
        *reinterpret_cast<float2*>(ob + (size_t)c * HW_) = o;
    }
}

extern "C" void kernel_launch(void* const* d_in, const int* in_sizes, int n_in,
                              void* d_out, int out_size, void* d_ws, size_t ws_size,
                              hipStream_t stream) {
    const float* orig   = (const float*)d_in[0];
    const float* deg    = (const float*)d_in[1];
    const float* logits = (const float*)d_in[2];
    const int*   topk   = (const int*)d_in[3];
    float* out = (float*)d_out;

    const int pairs = (512 * 512) / 2;             // 131072
    rain_combine_v3<<<dim3(pairs / 256, 4), dim3(256), 0, stream>>>(
        orig, deg, logits, topk, out);
}